// Round 1
// baseline (384.918 us; speedup 1.0000x reference)
//
#include <hip/hip_runtime.h>

// SGIntoKGPool: out[b,m,c] = (sum_n adj[b,n,m] * x[b,c,n]) / max(sum_n adj[b,n,m], 1)
// fp32 in / fp32 out. Internal compute: bf16 MFMA 16x16x32 with f32 accumulation.
//
// V2 structure: split-K x2 -> 512 blocks (2 blocks/CU) so barrier vmcnt-drains
// overlap across blocks; x B-operand loaded one iteration ahead into registers
// so packing never drains the adj prefetch early. Blocks write unnormalized
// partial sums + partial degrees to ws; norm_kernel reduces halves + divides.
//
// adj tile (64n x 64m fp32) transposed+converted into LDS bf16, swizzle:
//   element (m, nl) -> dword 36*m + 4*((nl>>3) ^ ((m>>2)&7)) + ((nl&7)>>1), half nl&1
// (verified conflict-free in previous session; unchanged here).

typedef short bf16x8 __attribute__((ext_vector_type(8)));
typedef float f32x4 __attribute__((ext_vector_type(4)));

#define BZc 8
#define Cc 64
#define Nc 4096
#define Mc 2048
#define BMc 64
#define BKc 64
#define NSPLIT 2
#define NHALF (Nc / NSPLIT)      // 2048
#define KITERS (NHALF / BKc)     // 32
#define SDW 36                   // adjT row stride in dwords (144 B, 16B-aligned)

#define PSUM_ELEMS (BZc * Mc * Cc)  // 1,048,576 floats per half
#define PDEG_ELEMS (BZc * Mc)       // 16,384 floats per half

// pack two fp32 -> dword with low16 = bf16(a), high16 = bf16(b); +0x8000 = round-to-nearest
__device__ __forceinline__ unsigned int pkbf(float a, float b) {
  unsigned int ua = __float_as_uint(a) + 0x8000u;
  unsigned int ub = __float_as_uint(b) + 0x8000u;
  return (ua >> 16) | (ub & 0xffff0000u);
}

__global__ __launch_bounds__(512, 4) void sgkg_kernel(
    const float* __restrict__ x,     // (BZ, C, N) fp32
    const float* __restrict__ adj,   // (BZ, N, M) fp32
    float* __restrict__ ws)          // psum[2][BZ*M*C], pdeg[2][BZ*M]
{
  __shared__ unsigned int adjT[BMc * SDW];    // 9216 B
  __shared__ float degs[BMc];

  const int t = threadIdx.x;
  const int l = t & 63;
  const int w = t >> 6;

  const int bz     = blockIdx.x >> 6;               // 64 blocks per batch
  const int m_base = ((blockIdx.x >> 1) & 31) * BMc;
  const int kh     = blockIdx.x & 1;                // n-half

  // ---- staging mapping: thread -> (mg: 4-m group, p: n-row pair) ----
  const int mg  = ((w & 1) << 3) | (l & 7);   // 0..15
  const int p   = ((w >> 1) << 3) | (l >> 3); // 0..31
  const int sm0 = mg << 2;                    // local m of first of 4 values

  const float* aptr =
      adj + (size_t)bz * Nc * Mc + (size_t)(kh * NHALF + 2 * p) * Mc + (m_base + sm0);
  // write base dword: j-th write goes to wb + j*SDW (m = sm0+j)
  const int wb = SDW * sm0 + ((((p >> 2) ^ (mg & 7))) << 2) + (p & 3);

  // ---- compute mapping: wave = 32m x 16c ----
  const int m_off = (w & 1) << 5;   // 0 or 32
  const int c_b   = (w >> 1) << 4;  // 0,16,32,48
  const int l15   = l & 15;
  const int l4    = l >> 4;

  // B-fragment global base: row c = c_b + l15, k offset l4*8, n-half offset
  const float* xb =
      x + ((size_t)bz * Cc + (c_b + l15)) * Nc + kh * NHALF + (l4 << 3);

  // A-fragment LDS dword addresses, per (tm, kstep)
  int aaddr[2][2];
#pragma unroll
  for (int tm = 0; tm < 2; ++tm) {
    const int m  = m_off + tm * 16 + l15;
    const int pi = (m >> 2) & 7;
    aaddr[tm][0] = SDW * m + (((l4) ^ pi) << 2);
    aaddr[tm][1] = SDW * m + (((4 + l4) ^ pi) << 2);
  }

  if (t < BMc) degs[t] = 0.0f;

  f32x4 acc0 = {0.f, 0.f, 0.f, 0.f};
  f32x4 acc1 = {0.f, 0.f, 0.f, 0.f};
  float dacc0 = 0.f, dacc1 = 0.f, dacc2 = 0.f, dacc3 = 0.f;

  // prefetch first adj tile (2 n-rows x 4 m, fp32)
  float4 r0 = *(const float4*)aptr;
  float4 r1 = *(const float4*)(aptr + Mc);
  // prefetch first x fragments (one iteration's worth, raw fp32 in regs)
  float4 xr0 = *(const float4*)(xb);
  float4 xr1 = *(const float4*)(xb + 4);
  float4 xr2 = *(const float4*)(xb + 32);
  float4 xr3 = *(const float4*)(xb + 36);

  for (int it = 0; it < KITERS; ++it) {
    __syncthreads();  // previous iter done reading adjT (also covers degs init)

    // ---- stage transposed+converted: dword = (bf16 adj[n][m], bf16 adj[n+1][m]) ----
    adjT[wb          ] = pkbf(r0.x, r1.x);
    adjT[wb +     SDW] = pkbf(r0.y, r1.y);
    adjT[wb + 2 * SDW] = pkbf(r0.z, r1.z);
    adjT[wb + 3 * SDW] = pkbf(r0.w, r1.w);

    // ---- degrees (exact fp32) for the 4 m's this thread stages ----
    dacc0 += r0.x + r1.x;
    dacc1 += r0.y + r1.y;
    dacc2 += r0.z + r1.z;
    dacc3 += r0.w + r1.w;

    // ---- prefetch next adj tile (dummy re-read on last iter) ----
    const float* anext = (it + 1 < KITERS) ? (aptr + (size_t)BKc * Mc) : aptr;
    float4 s0 = *(const float4*)anext;
    float4 s1 = *(const float4*)(anext + Mc);

    // ---- prefetch next x fragments (dummy re-read on last iter) ----
    const float* xnp = (it + 1 < KITERS) ? (xb + (it + 1) * BKc) : xb;
    float4 y0 = *(const float4*)(xnp);
    float4 y1 = *(const float4*)(xnp + 4);
    float4 y2 = *(const float4*)(xnp + 32);
    float4 y3 = *(const float4*)(xnp + 36);

    // ---- B fragments for this iter from registers (no vmem wait here) ----
    union { uint4 u; bf16x8 v; } B0, B1;
    B0.u = make_uint4(pkbf(xr0.x, xr0.y), pkbf(xr0.z, xr0.w),
                      pkbf(xr1.x, xr1.y), pkbf(xr1.z, xr1.w));
    B1.u = make_uint4(pkbf(xr2.x, xr2.y), pkbf(xr2.z, xr2.w),
                      pkbf(xr3.x, xr3.y), pkbf(xr3.z, xr3.w));

    __syncthreads();  // adjT writes visible

    // ---- MFMA: 2 m-tiles x 2 k-steps ----
    bf16x8 a00 = *(const bf16x8*)(adjT + aaddr[0][0]);
    bf16x8 a10 = *(const bf16x8*)(adjT + aaddr[1][0]);
    acc0 = __builtin_amdgcn_mfma_f32_16x16x32_bf16(a00, B0.v, acc0, 0, 0, 0);
    acc1 = __builtin_amdgcn_mfma_f32_16x16x32_bf16(a10, B0.v, acc1, 0, 0, 0);
    bf16x8 a01 = *(const bf16x8*)(adjT + aaddr[0][1]);
    bf16x8 a11 = *(const bf16x8*)(adjT + aaddr[1][1]);
    acc0 = __builtin_amdgcn_mfma_f32_16x16x32_bf16(a01, B1.v, acc0, 0, 0, 0);
    acc1 = __builtin_amdgcn_mfma_f32_16x16x32_bf16(a11, B1.v, acc1, 0, 0, 0);

    aptr = anext;
    r0 = s0; r1 = s1;
    xr0 = y0; xr1 = y1; xr2 = y2; xr3 = y3;
  }

  // ---- degree reduction (partial, this n-half) ----
  __syncthreads();
  atomicAdd(&degs[sm0 + 0], dacc0);
  atomicAdd(&degs[sm0 + 1], dacc1);
  atomicAdd(&degs[sm0 + 2], dacc2);
  atomicAdd(&degs[sm0 + 3], dacc3);

  // ---- store unnormalized partial sums (no degs dependency) ----
  float* psum = ws + (size_t)kh * PSUM_ELEMS;
  // D layout (16x16x32): col = l&15 (c), row = (l>>4)*4 + r (m)
#pragma unroll
  for (int tm = 0; tm < 2; ++tm) {
    const f32x4 acc = tm ? acc1 : acc0;
#pragma unroll
    for (int r = 0; r < 4; ++r) {
      const int ml   = m_off + tm * 16 + (l4 << 2) + r;
      const size_t o = ((size_t)(bz * Mc + m_base + ml)) * Cc + (c_b + l15);
      psum[o] = acc[r];
    }
  }

  __syncthreads();
  if (t < BMc) {
    float* pdeg = ws + 2 * (size_t)PSUM_ELEMS + (size_t)kh * PDEG_ELEMS;
    pdeg[bz * Mc + m_base + t] = degs[t];
  }
}

__global__ __launch_bounds__(256) void norm_kernel(
    const float* __restrict__ ws, float* __restrict__ out)
{
  const int i = blockIdx.x * 256 + threadIdx.x;       // float4 index, 262144 total
  const float4* p0 = (const float4*)ws;
  const float4* p1 = (const float4*)(ws + PSUM_ELEMS);
  const float* d0  = ws + 2 * (size_t)PSUM_ELEMS;
  const float* d1  = d0 + PDEG_ELEMS;

  const int bm = i >> 4;                               // (i*4)/Cc
  const float den = fmaxf(d0[bm] + d1[bm], 1.0f);

  float4 a = p0[i];
  float4 b = p1[i];
  float4 r;
  r.x = (a.x + b.x) / den;
  r.y = (a.y + b.y) / den;
  r.z = (a.z + b.z) / den;
  r.w = (a.w + b.w) / den;
  ((float4*)out)[i] = r;
}

extern "C" void kernel_launch(void* const* d_in, const int* in_sizes, int n_in,
                              void* d_out, int out_size, void* d_ws, size_t ws_size,
                              hipStream_t stream) {
  const float* x   = (const float*)d_in[0];  // sg_node_feats (8,64,64,64) fp32
  const float* adj = (const float*)d_in[1];  // sg_kg_adj (8,4096,2048) fp32
  float* out       = (float*)d_out;          // (8,2048,64) fp32
  float* ws        = (float*)d_ws;           // >= (2*PSUM_ELEMS + 2*PDEG_ELEMS)*4 B = 8.5 MB
  (void)in_sizes; (void)n_in; (void)out_size; (void)ws_size;

  sgkg_kernel<<<dim3(BZc * (Mc / BMc) * NSPLIT), dim3(512), 0, stream>>>(x, adj, ws);
  norm_kernel<<<dim3(PSUM_ELEMS / 4 / 256), dim3(256), 0, stream>>>(ws, out);
}

// Round 2
// 378.778 us; speedup vs baseline: 1.0162x; 1.0162x over previous
//
#include <hip/hip_runtime.h>

// SGIntoKGPool: out[b,m,c] = (sum_n adj[b,n,m] * x[b,c,n]) / max(sum_n adj[b,n,m], 1)
// fp32 in / fp32 out. Internal compute: bf16 MFMA 16x16x32 with f32 accumulation.
//
// V3: attack DRAM page efficiency on the adj read. Per-block m-slice widened
// 64 -> 128 (two verified 64-m swizzled panels), so each adj row-visit is a
// 512 B contiguous chunk (was 256 B) and only 16 blocks share a row (was 32).
// Split-n x4 keeps 512 blocks (2/CU at <=128 VGPR). x loads issued at iter
// top (before barrier) each iter -- no cross-iter x prefetch, keeps VGPR low;
// counted vmcnt keeps adj prefetch in flight past the x wait.
// Blocks write unnormalized partial sums + partial degrees; norm_kernel reduces.
//
// adj panel (64n x 64m fp32) transposed+converted into LDS bf16, swizzle
// (verified conflict-free in earlier rounds, unchanged):
//   element (m, nl) -> dword 36*m + 4*((nl>>3) ^ ((m>>2)&7)) + ((nl&7)>>1), half nl&1

typedef short bf16x8 __attribute__((ext_vector_type(8)));
typedef float f32x4 __attribute__((ext_vector_type(4)));

#define BZc 8
#define Cc 64
#define Nc 4096
#define Mc 2048
#define BMc 128                  // m per block = 2 panels of 64
#define BKc 64
#define NSPLIT 4
#define NSEG (Nc / NSPLIT)       // 1024 n per block
#define KITERS (NSEG / BKc)      // 16
#define SDW 36                   // adjT row stride in dwords (144 B, 16B-aligned)
#define PANEL (64 * SDW)         // dwords per 64-m panel

#define PSUM_ELEMS (BZc * Mc * Cc)  // 1,048,576 floats per split
#define PDEG_ELEMS (BZc * Mc)       // 16,384 floats per split

// pack two fp32 -> dword with low16 = bf16(a), high16 = bf16(b); +0x8000 = round-to-nearest
__device__ __forceinline__ unsigned int pkbf(float a, float b) {
  unsigned int ua = __float_as_uint(a) + 0x8000u;
  unsigned int ub = __float_as_uint(b) + 0x8000u;
  return (ua >> 16) | (ub & 0xffff0000u);
}

__global__ __launch_bounds__(512, 4) void sgkg_kernel(
    const float* __restrict__ x,     // (BZ, C, N) fp32
    const float* __restrict__ adj,   // (BZ, N, M) fp32
    float* __restrict__ ws)          // psum[4][BZ*M*C], pdeg[4][BZ*M]
{
  __shared__ unsigned int adjT[2 * PANEL];    // 18432 B
  __shared__ float degs[BMc];

  const int t = threadIdx.x;
  const int l = t & 63;
  const int w = t >> 6;

  const int bz     = blockIdx.x >> 6;          // 64 blocks per batch
  const int mb     = (blockIdx.x >> 2) & 15;   // 16 m-blocks of 128
  const int kh     = blockIdx.x & 3;           // n-quarter
  const int m_base = mb * BMc;

  // ---- staging mapping: thread -> (mg: 4-m group, p: n-row pair), x2 panels ----
  const int mg  = ((w & 1) << 3) | (l & 7);   // 0..15
  const int p   = ((w >> 1) << 3) | (l >> 3); // 0..31
  const int sm0 = mg << 2;                    // local m (within panel) of first of 4

  const float* aptr =
      adj + (size_t)bz * Nc * Mc + (size_t)(kh * NSEG + 2 * p) * Mc + (m_base + sm0);
  // write base dword within a panel: j-th write goes to wb + j*SDW (m = sm0+j)
  const int wb = SDW * sm0 + (((p >> 2) ^ (mg & 7)) << 2) + (p & 3);

  // ---- compute mapping: 8 waves = 4 m-offsets x 2 c-halves; wave = 32m x 32c ----
  const int m_off = (w & 3) << 5;   // 0,32,64,96
  const int c_b   = (w >> 2) << 5;  // 0 or 32
  const int l15   = l & 15;
  const int l4    = l >> 4;

  // B-fragment global base: row c = c_b + l15 (ct adds +16 rows), k offset l4*8
  const float* xb =
      x + ((size_t)bz * Cc + (c_b + l15)) * Nc + kh * NSEG + (l4 << 3);

  // A-fragment LDS dword addresses, per (tm, kstep); panel-aware
  int aaddr[2][2];
#pragma unroll
  for (int tm = 0; tm < 2; ++tm) {
    const int m  = m_off + tm * 16 + l15;     // 0..127
    const int q  = m >> 6;                    // panel
    const int ml = m & 63;
    const int pi = (ml >> 2) & 7;
    aaddr[tm][0] = q * PANEL + SDW * ml + ((l4 ^ pi) << 2);
    aaddr[tm][1] = q * PANEL + SDW * ml + (((4 + l4) ^ pi) << 2);
  }

  if (t < BMc) degs[t] = 0.0f;

  f32x4 acc00 = {0.f,0.f,0.f,0.f}, acc01 = {0.f,0.f,0.f,0.f};
  f32x4 acc10 = {0.f,0.f,0.f,0.f}, acc11 = {0.f,0.f,0.f,0.f};
  float da00=0.f, da01=0.f, da02=0.f, da03=0.f;   // panel0 degrees
  float da10=0.f, da11=0.f, da12=0.f, da13=0.f;   // panel1 degrees

  // prefetch first adj tile: 2 rows x 4 m x 2 panels (panel1 at +64 floats)
  float4 r00 = *(const float4*)(aptr);
  float4 r01 = *(const float4*)(aptr + Mc);
  float4 r10 = *(const float4*)(aptr + 64);
  float4 r11 = *(const float4*)(aptr + 64 + Mc);

  for (int it = 0; it < KITERS; ++it) {
    // ---- x loads for THIS iter, issued before the barrier (overlap) ----
    const float* xit0 = xb + it * BKc;            // ct = 0
    const float* xit1 = xit0 + 16 * Nc;           // ct = 1
    float4 x00 = *(const float4*)(xit0);
    float4 x01 = *(const float4*)(xit0 + 4);
    float4 x02 = *(const float4*)(xit0 + 32);
    float4 x03 = *(const float4*)(xit0 + 36);
    float4 x10 = *(const float4*)(xit1);
    float4 x11 = *(const float4*)(xit1 + 4);
    float4 x12 = *(const float4*)(xit1 + 32);
    float4 x13 = *(const float4*)(xit1 + 36);

    __syncthreads();  // previous iter done reading adjT (also covers degs init)

    // ---- stage transposed+converted, both panels ----
    adjT[wb          ]         = pkbf(r00.x, r01.x);
    adjT[wb +     SDW]         = pkbf(r00.y, r01.y);
    adjT[wb + 2 * SDW]         = pkbf(r00.z, r01.z);
    adjT[wb + 3 * SDW]         = pkbf(r00.w, r01.w);
    adjT[PANEL + wb          ] = pkbf(r10.x, r11.x);
    adjT[PANEL + wb +     SDW] = pkbf(r10.y, r11.y);
    adjT[PANEL + wb + 2 * SDW] = pkbf(r10.z, r11.z);
    adjT[PANEL + wb + 3 * SDW] = pkbf(r10.w, r11.w);

    // ---- degrees (exact fp32) ----
    da00 += r00.x + r01.x;  da01 += r00.y + r01.y;
    da02 += r00.z + r01.z;  da03 += r00.w + r01.w;
    da10 += r10.x + r11.x;  da11 += r10.y + r11.y;
    da12 += r10.z + r11.z;  da13 += r10.w + r11.w;

    // ---- prefetch next adj tile (dummy re-read on last iter) ----
    const float* anext = (it + 1 < KITERS) ? (aptr + (size_t)BKc * Mc) : aptr;
    float4 s00 = *(const float4*)(anext);
    float4 s01 = *(const float4*)(anext + Mc);
    float4 s10 = *(const float4*)(anext + 64);
    float4 s11 = *(const float4*)(anext + 64 + Mc);

    // ---- B fragments (waits on x loads; adj prefetch stays in flight) ----
    union { uint4 u; bf16x8 v; } B00, B01, B10, B11;   // B<ct><kstep>
    B00.u = make_uint4(pkbf(x00.x, x00.y), pkbf(x00.z, x00.w),
                       pkbf(x01.x, x01.y), pkbf(x01.z, x01.w));
    B01.u = make_uint4(pkbf(x02.x, x02.y), pkbf(x02.z, x02.w),
                       pkbf(x03.x, x03.y), pkbf(x03.z, x03.w));
    B10.u = make_uint4(pkbf(x10.x, x10.y), pkbf(x10.z, x10.w),
                       pkbf(x11.x, x11.y), pkbf(x11.z, x11.w));
    B11.u = make_uint4(pkbf(x12.x, x12.y), pkbf(x12.z, x12.w),
                       pkbf(x13.x, x13.y), pkbf(x13.z, x13.w));

    __syncthreads();  // adjT writes visible

    // ---- MFMA: 2 m-tiles x 2 c-tiles x 2 k-steps ----
    bf16x8 a00 = *(const bf16x8*)(adjT + aaddr[0][0]);
    bf16x8 a10 = *(const bf16x8*)(adjT + aaddr[1][0]);
    acc00 = __builtin_amdgcn_mfma_f32_16x16x32_bf16(a00, B00.v, acc00, 0, 0, 0);
    acc01 = __builtin_amdgcn_mfma_f32_16x16x32_bf16(a00, B10.v, acc01, 0, 0, 0);
    acc10 = __builtin_amdgcn_mfma_f32_16x16x32_bf16(a10, B00.v, acc10, 0, 0, 0);
    acc11 = __builtin_amdgcn_mfma_f32_16x16x32_bf16(a10, B10.v, acc11, 0, 0, 0);
    bf16x8 a01 = *(const bf16x8*)(adjT + aaddr[0][1]);
    bf16x8 a11 = *(const bf16x8*)(adjT + aaddr[1][1]);
    acc00 = __builtin_amdgcn_mfma_f32_16x16x32_bf16(a01, B01.v, acc00, 0, 0, 0);
    acc01 = __builtin_amdgcn_mfma_f32_16x16x32_bf16(a01, B11.v, acc01, 0, 0, 0);
    acc10 = __builtin_amdgcn_mfma_f32_16x16x32_bf16(a11, B01.v, acc10, 0, 0, 0);
    acc11 = __builtin_amdgcn_mfma_f32_16x16x32_bf16(a11, B11.v, acc11, 0, 0, 0);

    aptr = anext;
    r00 = s00; r01 = s01; r10 = s10; r11 = s11;
  }

  // ---- degree reduction (partial, this n-quarter) ----
  __syncthreads();
  atomicAdd(&degs[     sm0 + 0], da00);
  atomicAdd(&degs[     sm0 + 1], da01);
  atomicAdd(&degs[     sm0 + 2], da02);
  atomicAdd(&degs[     sm0 + 3], da03);
  atomicAdd(&degs[64 + sm0 + 0], da10);
  atomicAdd(&degs[64 + sm0 + 1], da11);
  atomicAdd(&degs[64 + sm0 + 2], da12);
  atomicAdd(&degs[64 + sm0 + 3], da13);

  // ---- store unnormalized partial sums ----
  float* psum = ws + (size_t)kh * PSUM_ELEMS;
  // D layout (16x16x32): col = l&15 (c), row = (l>>4)*4 + r (m)
#pragma unroll
  for (int tm = 0; tm < 2; ++tm) {
#pragma unroll
    for (int ct = 0; ct < 2; ++ct) {
      const f32x4 acc = tm ? (ct ? acc11 : acc10) : (ct ? acc01 : acc00);
#pragma unroll
      for (int r = 0; r < 4; ++r) {
        const int ml   = m_off + tm * 16 + (l4 << 2) + r;
        const int c    = c_b + ct * 16 + l15;
        const size_t o = ((size_t)(bz * Mc + m_base + ml)) * Cc + c;
        psum[o] = acc[r];
      }
    }
  }

  __syncthreads();
  if (t < BMc) {
    float* pdeg = ws + (size_t)NSPLIT * PSUM_ELEMS + (size_t)kh * PDEG_ELEMS;
    pdeg[bz * Mc + m_base + t] = degs[t];
  }
}

__global__ __launch_bounds__(256) void norm_kernel(
    const float* __restrict__ ws, float* __restrict__ out)
{
  const int i = blockIdx.x * 256 + threadIdx.x;       // float4 index, 262144 total
  const float4* p0 = (const float4*)(ws);
  const float4* p1 = (const float4*)(ws + (size_t)1 * PSUM_ELEMS);
  const float4* p2 = (const float4*)(ws + (size_t)2 * PSUM_ELEMS);
  const float4* p3 = (const float4*)(ws + (size_t)3 * PSUM_ELEMS);
  const float* dg  = ws + (size_t)NSPLIT * PSUM_ELEMS;

  const int bm = i >> 4;                               // (i*4)/Cc
  const float den = fmaxf(dg[bm] + dg[PDEG_ELEMS + bm] +
                          dg[2 * PDEG_ELEMS + bm] + dg[3 * PDEG_ELEMS + bm], 1.0f);

  float4 a = p0[i];
  float4 b = p1[i];
  float4 c = p2[i];
  float4 d = p3[i];
  float4 r;
  r.x = (a.x + b.x + c.x + d.x) / den;
  r.y = (a.y + b.y + c.y + d.y) / den;
  r.z = (a.z + b.z + c.z + d.z) / den;
  r.w = (a.w + b.w + c.w + d.w) / den;
  ((float4*)out)[i] = r;
}

extern "C" void kernel_launch(void* const* d_in, const int* in_sizes, int n_in,
                              void* d_out, int out_size, void* d_ws, size_t ws_size,
                              hipStream_t stream) {
  const float* x   = (const float*)d_in[0];  // sg_node_feats (8,64,64,64) fp32
  const float* adj = (const float*)d_in[1];  // sg_kg_adj (8,4096,2048) fp32
  float* out       = (float*)d_out;          // (8,2048,64) fp32
  float* ws        = (float*)d_ws;           // >= (4*PSUM + 4*PDEG)*4 B = 16.3 MB
  (void)in_sizes; (void)n_in; (void)out_size; (void)ws_size;

  sgkg_kernel<<<dim3(BZc * (Mc / BMc) * NSPLIT), dim3(512), 0, stream>>>(x, adj, ws);
  norm_kernel<<<dim3(PSUM_ELEMS / 4 / 256), dim3(256), 0, stream>>>(ws, out);
}

// Round 4
// 365.527 us; speedup vs baseline: 1.0530x; 1.0363x over previous
//
#include <hip/hip_runtime.h>

// SGIntoKGPool: out[b,m,c] = (sum_n adj[b,n,m] * x[b,c,n]) / max(sum_n adj[b,n,m], 1)
// fp32 in / fp32 out. Internal compute: bf16 MFMA 16x16x32 with f32 accumulation.
//
// V5 = V4 with the staging row-mapping bug fixed (V4 read OOB + non-bijective).
// Chunk-size probe vs r2: per-block m-slice 256 (4 x 64-m panels); each adj
// global-read instruction is ONE ROW x 1024 B contiguous (64 lanes x float4):
//   wave w, unroll j: rows 8w + 2j + {0,1}; lane l: cols 4l..4l+3.
// Bijective over the 64x256 tile (8w+2j+pair -> 0..63; 4l+jm -> 0..255).
// NSPLIT=4 and psum/norm identical to r2 so the A/B isolates chunk size.
//
// LDS: 4 panels, session-verified per-panel transpose swizzle:
//   element (m, nl) -> dword q*PSTRIDE + 36*m + 4*((nl>>3) ^ ((m>>2)&7)) + ((nl&7)>>1),
//   half nl&1.  Writes here: m = 4*(l&15)+jm (pi = l&7), nl>>3 = w, (nl&7)>>1 = j.
//   PSTRIDE = 64*36+4 keeps 16B alignment for b128 reads; write conflicts <=4-way
//   (writes are ~2% of the iter budget; kernel is HBM-bound).

typedef short bf16x8 __attribute__((ext_vector_type(8)));
typedef float f32x4 __attribute__((ext_vector_type(4)));

#define BZc 8
#define Cc 64
#define Nc 4096
#define Mc 2048
#define BMc 256                  // m per block = 4 panels of 64
#define BKc 64
#define NSPLIT 4
#define NSEG (Nc / NSPLIT)       // 1024 n per block
#define KITERS (NSEG / BKc)      // 16
#define SDW 36                   // adjT row stride in dwords (144 B, 16B-aligned)
#define PSTRIDE (64 * SDW + 4)   // 2308 dw per panel
#define NPAN 4

#define PSUM_ELEMS (BZc * Mc * Cc)  // 1,048,576 floats per split
#define PDEG_ELEMS (BZc * Mc)       // 16,384 floats per split

// pack two fp32 -> dword with low16 = bf16(a), high16 = bf16(b); +0x8000 = round-to-nearest
__device__ __forceinline__ unsigned int pkbf(float a, float b) {
  unsigned int ua = __float_as_uint(a) + 0x8000u;
  unsigned int ub = __float_as_uint(b) + 0x8000u;
  return (ua >> 16) | (ub & 0xffff0000u);
}

__global__ __launch_bounds__(512, 2) void sgkg_kernel(
    const float* __restrict__ x,     // (BZ, C, N) fp32
    const float* __restrict__ adj,   // (BZ, N, M) fp32
    float* __restrict__ ws)          // psum[4][BZ*M*C], pdeg[4][BZ*M]
{
  __shared__ unsigned int adjT[NPAN * PSTRIDE];   // 36928 B
  __shared__ float degs[BMc];                     // 1024 B

  const int t = threadIdx.x;
  const int l = t & 63;
  const int w = t >> 6;

  const int bz     = blockIdx.x >> 5;          // 32 blocks per batch
  const int mb     = (blockIdx.x >> 2) & 7;    // 8 m-blocks of 256
  const int kh     = blockIdx.x & 3;           // n-quarter
  const int m_base = mb * BMc;

  // ---- staging mapping: wave w -> rows 8w+2j+{0,1}; lane l -> cols 4l..4l+3 ----
  const int q   = l >> 4;                      // panel 0..3
  const int sm0 = (l & 15) << 2;               // local m within panel
  const int pi  = l & 7;                       // swizzle index of these 4 m's
  const int lm0 = l << 2;                      // block-local col of first of 4

  const float* ap =
      adj + ((size_t)bz * Nc + kh * NSEG + 8 * w) * Mc + (m_base + lm0);
  const int wbase = q * PSTRIDE + SDW * sm0 + ((w ^ pi) << 2);

  // ---- compute mapping: wave = (m-half mh, c-quad cq); 8 m-tiles x 1 c-tile ----
  const int mh  = w >> 2;           // 0..1 -> m 0..127 / 128..255
  const int cq  = w & 3;
  const int c_b = cq << 4;
  const int l15 = l & 15;
  const int l4  = l >> 4;

  const float* xb =
      x + ((size_t)bz * Cc + (c_b + l15)) * Nc + kh * NSEG + (l4 << 3);

  // A-fragment LDS dword offsets within a panel, per (tm&3, kstep)
  int abase[4][2];
#pragma unroll
  for (int k = 0; k < 4; ++k) {
    const int ml = k * 16 + l15;
    const int pr = (ml >> 2) & 7;
    abase[k][0] = SDW * ml + ((l4 ^ pr) << 2);
    abase[k][1] = SDW * ml + (((4 + l4) ^ pr) << 2);
  }

  if (t < BMc) degs[t] = 0.0f;

  f32x4 acc[8];
#pragma unroll
  for (int i = 0; i < 8; ++i) acc[i] = (f32x4){0.f, 0.f, 0.f, 0.f};
  float dacc0 = 0.f, dacc1 = 0.f, dacc2 = 0.f, dacc3 = 0.f;

  // ---- prologue: prefetch iter-0 adj rows (4 row-pairs x 4 cols) ----
  float4 R0[4], R1[4], S0[4], S1[4];
#pragma unroll
  for (int j = 0; j < 4; ++j) {
    const float* pj = ap + (size_t)(2 * j) * Mc;
    R0[j] = *(const float4*)pj;
    R1[j] = *(const float4*)(pj + Mc);
  }

  for (int it = 0; it < KITERS; ++it) {
    // ---- x loads for this iter (L2-resident across m-blocks) ----
    const float* xit = xb + it * BKc;
    float4 xa = *(const float4*)(xit);
    float4 xbv = *(const float4*)(xit + 4);
    float4 xc = *(const float4*)(xit + 32);
    float4 xd = *(const float4*)(xit + 36);

    __syncthreads();  // previous iter done reading adjT (also covers degs init)

    // ---- stage transposed+converted + degrees ----
#pragma unroll
    for (int j = 0; j < 4; ++j) {
      const int wj = wbase + j;
      adjT[wj          ] = pkbf(R0[j].x, R1[j].x);
      adjT[wj +     SDW] = pkbf(R0[j].y, R1[j].y);
      adjT[wj + 2 * SDW] = pkbf(R0[j].z, R1[j].z);
      adjT[wj + 3 * SDW] = pkbf(R0[j].w, R1[j].w);
      dacc0 += R0[j].x + R1[j].x;
      dacc1 += R0[j].y + R1[j].y;
      dacc2 += R0[j].z + R1[j].z;
      dacc3 += R0[j].w + R1[j].w;
    }

    // ---- prefetch next adj tile (dummy re-read on last iter) ----
    const int itn = (it + 1 < KITERS) ? (it + 1) : it;
#pragma unroll
    for (int j = 0; j < 4; ++j) {
      const float* pj = ap + (size_t)(itn * BKc + 2 * j) * Mc;
      S0[j] = *(const float4*)pj;
      S1[j] = *(const float4*)(pj + Mc);
    }

    // ---- B fragments ----
    union { uint4 u; bf16x8 v; } B0, B1;
    B0.u = make_uint4(pkbf(xa.x, xa.y), pkbf(xa.z, xa.w),
                      pkbf(xbv.x, xbv.y), pkbf(xbv.z, xbv.w));
    B1.u = make_uint4(pkbf(xc.x, xc.y), pkbf(xc.z, xc.w),
                      pkbf(xd.x, xd.y), pkbf(xd.z, xd.w));

    __syncthreads();  // adjT writes visible

    // ---- MFMA: 8 m-tiles x 2 k-steps ----
#pragma unroll
    for (int tm = 0; tm < 8; ++tm) {
      const int qo = ((mh << 1) + (tm >> 2)) * PSTRIDE;
      bf16x8 a0 = *(const bf16x8*)(adjT + qo + abase[tm & 3][0]);
      acc[tm] = __builtin_amdgcn_mfma_f32_16x16x32_bf16(a0, B0.v, acc[tm], 0, 0, 0);
      bf16x8 a1 = *(const bf16x8*)(adjT + qo + abase[tm & 3][1]);
      acc[tm] = __builtin_amdgcn_mfma_f32_16x16x32_bf16(a1, B1.v, acc[tm], 0, 0, 0);
    }

#pragma unroll
    for (int j = 0; j < 4; ++j) { R0[j] = S0[j]; R1[j] = S1[j]; }
  }

  // ---- degree reduction (partial, this n-quarter) ----
  __syncthreads();
  atomicAdd(&degs[lm0 + 0], dacc0);
  atomicAdd(&degs[lm0 + 1], dacc1);
  atomicAdd(&degs[lm0 + 2], dacc2);
  atomicAdd(&degs[lm0 + 3], dacc3);

  // ---- store unnormalized partial sums ----
  float* psum = ws + (size_t)kh * PSUM_ELEMS;
  // D layout (16x16x32): col = l&15 (c), row = (l>>4)*4 + r (m)
#pragma unroll
  for (int tm = 0; tm < 8; ++tm) {
#pragma unroll
    for (int r = 0; r < 4; ++r) {
      const int ml   = (mh << 7) + tm * 16 + (l4 << 2) + r;
      const size_t o = ((size_t)(bz * Mc + m_base + ml)) * Cc + (c_b + l15);
      psum[o] = acc[tm][r];
    }
  }

  __syncthreads();
  if (t < BMc) {
    float* pdeg = ws + (size_t)NSPLIT * PSUM_ELEMS + (size_t)kh * PDEG_ELEMS;
    pdeg[bz * Mc + m_base + t] = degs[t];
  }
}

__global__ __launch_bounds__(256) void norm_kernel(
    const float* __restrict__ ws, float* __restrict__ out)
{
  const int i = blockIdx.x * 256 + threadIdx.x;       // float4 index, 262144 total
  const float4* p0 = (const float4*)(ws);
  const float4* p1 = (const float4*)(ws + (size_t)1 * PSUM_ELEMS);
  const float4* p2 = (const float4*)(ws + (size_t)2 * PSUM_ELEMS);
  const float4* p3 = (const float4*)(ws + (size_t)3 * PSUM_ELEMS);
  const float* dg  = ws + (size_t)NSPLIT * PSUM_ELEMS;

  const int bm = i >> 4;                               // (i*4)/Cc
  const float den = fmaxf(dg[bm] + dg[PDEG_ELEMS + bm] +
                          dg[2 * PDEG_ELEMS + bm] + dg[3 * PDEG_ELEMS + bm], 1.0f);

  float4 a = p0[i];
  float4 b = p1[i];
  float4 c = p2[i];
  float4 d = p3[i];
  float4 r;
  r.x = (a.x + b.x + c.x + d.x) / den;
  r.y = (a.y + b.y + c.y + d.y) / den;
  r.z = (a.z + b.z + c.z + d.z) / den;
  r.w = (a.w + b.w + c.w + d.w) / den;
  ((float4*)out)[i] = r;
}

extern "C" void kernel_launch(void* const* d_in, const int* in_sizes, int n_in,
                              void* d_out, int out_size, void* d_ws, size_t ws_size,
                              hipStream_t stream) {
  const float* x   = (const float*)d_in[0];  // sg_node_feats (8,64,64,64) fp32
  const float* adj = (const float*)d_in[1];  // sg_kg_adj (8,4096,2048) fp32
  float* out       = (float*)d_out;          // (8,2048,64) fp32
  float* ws        = (float*)d_ws;           // >= (4*PSUM + 4*PDEG)*4 B = 17.1 MB
  (void)in_sizes; (void)n_in; (void)out_size; (void)ws_size;

  sgkg_kernel<<<dim3(BZc * (Mc / BMc) * NSPLIT), dim3(512), 0, stream>>>(x, adj, ws);
  norm_kernel<<<dim3(PSUM_ELEMS / 4 / 256), dim3(256), 0, stream>>>(ws, out);
}